// Round 12
// baseline (340.318 us; speedup 1.0000x reference)
//
#include <hip/hip_runtime.h>
#include <math.h>

#define NN   1024
#define DD   32
#define EE   32768

// ---- workspace float offsets ----
#define O_LAMP 0             // NN*32  lamp: lane0=lam-1, 1..31=lam*p (== in_emb)
#define O_PARR 32768         // NN*32  parr: lane0=artanh(wn)/wn, 1..31=p_in
#define O_PN2  65536         // NN     |p_in|^2
#define O_AB   66560         // NN*64  per-node Wa half-dots [A(32) | B(32)]
#define O_PART 132096        // 256*32 colsum partials [blk][col]
#define O_NUMB 140288        // NN*32 (col0=den)          -- zero region start
#define O_ASUM 173056        // EE*32
#define O_CCNT 1221632       // NN*NN ints: low16=cnt, high bits=deposits
#define O_ROWC 2270208       // NN ints: unique cells per row
#define O_NDEP 2271232       // NN ints: numb contributions -- zero region end
#define O_SLOT 2272256       // NN*NN ints (claimed in k_b; NO init)
#define ZERO_I4 ((O_SLOT - O_NUMB)/4)   // 532992

__device__ __forceinline__ float artanh_f(float x){
    x = fminf(fmaxf(x, -1.f + 1e-7f), 1.f - 1e-7f);
    return 0.5f * (log1pf(x) - log1pf(-x));
}
__device__ __forceinline__ float arcosh_f(float x){
    x = fmaxf(x, 1.f + 1e-7f);
    return logf(x + sqrtf(x*x - 1.f));
}
__device__ __forceinline__ float rsum(float v){
#pragma unroll
    for (int off=16; off>0; off>>=1) v += __shfl_xor(v, off, 32);
    return v;
}
__device__ __forceinline__ float logmap0_l(float xv, int lane){
    float ss = rsum(lane>=1 ? xv*xv : 0.f);
    float yn = sqrtf(fmaxf(ss, 1e-15f));
    float x0 = __shfl(xv, 0, 32);
    float s  = arcosh_f(x0) / yn;
    return lane>=1 ? s*xv : 0.f;
}
__device__ __forceinline__ float expmap0_proj_l(float uv, int lane){
    float ss = rsum(lane>=1 ? uv*uv : 0.f);
    float xn = sqrtf(fmaxf(ss, 1e-15f));
    float sh = sinhf(xn)/xn;
    float o  = sh*uv;
    float ys = rsum(lane>=1 ? o*o : 0.f);
    float o0 = sqrtf(fmaxf(1.f+ys, 1e-7f));
    return lane==0 ? o0 : o;
}
__device__ __forceinline__ float mobius_add_u_l(float xv, float uv, int lane){
    float u  = lane>=1 ? uv : 0.f;
    float x1 = lane>=1 ? xv : 0.f;
    float ss = rsum(x1*x1);
    float xn = sqrtf(fmaxf(ss, 1e-15f));
    float alpha = rsum(x1*u) / xn;
    float x0 = __shfl(xv, 0, 32);
    float coef = alpha * (1.f - x0) / xn;
    float w  = lane>=1 ? u - coef*xv : 0.f;
    float ux = rsum(x1*w);
    float w0 = ux / fmaxf(x0, 1e-7f);
    float wsq = rsum(w*w);
    float nu = sqrtf(fmaxf(wsq - w0*w0, 1e-15f));
    float th = fmaxf(nu, 1e-15f);
    float ch = coshf(th), shq = sinhf(th)/th;
    float o  = ch*xv + shq*w;
    float ys = rsum(lane>=1 ? o*o : 0.f);
    float o0 = sqrtf(fmaxf(1.f+ys, 1e-7f));
    return lane==0 ? o0 : o;
}
__device__ __forceinline__ float att_of(float ac, float w, float m, int lane){
    float ad = __shfl(ac,0,32)+1.f;
    float wd = m*__shfl(w,0,32)+1.f;
    float pa_ = lane>=1 ? ac/ad : 0.f;
    float pw  = lane>=1 ? m*w/wd : 0.f;
    float dot = rsum(pa_*pw);
    float wns = rsum(pw*pw);
    float wn  = sqrtf(fmaxf(wns, 1e-15f));
    return tanhf(dot/wn * artanh_f(wn));
}
__device__ __forceinline__ float edge_es(int i, int j, const float* __restrict__ pn2,
        const float* __restrict__ AB, int lane){
    float sq = pn2[i] + pn2[j];
    float dnm = fmaxf(1.f-sq, 1e-15f);
    float c0  = (1.f+sq)/dnm;
    float ssy = 4.f*sq/(dnm*dnm);
    float ynn = sqrtf(fmaxf(ssy, 1e-15f));
    float scl = arcosh_f(c0)/ynn * 2.f/dnm;     // sc2 * t2
    float v = scl*(AB[i*64+lane] + AB[j*64+32+lane]);
    v = v>=0.f ? v : 0.2f*v;                    // leaky (logmap/expmap cancel)
    return lane>=1 ? expf(v) : 0.f;             // bounded logits: no max pass
}
// per-node epilogue for node i (Wo/bo from global; numb via coherent loads)
__device__ __forceinline__ void node_epilogue(int i, int lane,
        const float* __restrict__ numb, const float* __restrict__ Wo,
        const float* __restrict__ bo, float* __restrict__ out){
    float nb = __hip_atomic_load(&numb[i*32+lane], __ATOMIC_RELAXED,
                                 __HIP_MEMORY_SCOPE_AGENT);
    float dn = __shfl(nb, 0, 32);
    if (fabsf(dn) < 1e-10f) dn = 1e-10f;
    float g = lane>=1 ? nb/dn : 0.f;
    float gss = rsum(g*g);
    float gn = sqrtf(fmaxf(gss, 1e-15f));
    float scl = tanhf(0.5f*artanh_f(gn))/gn;
    g *= scl;                                   // p_out
    float sq = rsum(g*g);
    float dnm = fmaxf(1.f-sq, 1e-15f);
    float h = lane==0 ? (1.f+sq)/dnm : 2.f*g/dnm;
    float r = logmap0_l(h, lane);
    float acc = 0.f;
#pragma unroll
    for (int d=1; d<32; ++d){ float rb = __shfl(r, d, 32); acc += Wo[lane*32+d]*rb; }
    float v = lane>=1 ? acc : 0.f;
    float res = expmap0_proj_l(v, lane);
    float o   = mobius_add_u_l(res, bo[lane], lane);
    out[i*32+lane] = o;
}

// ---- A: fill (blocks 128..1023) + per-node precompute (blocks 0..127) ----
__global__ __launch_bounds__(256) void k_a(const float* __restrict__ x,
        const float* __restrict__ Wd, const float* __restrict__ bd,
        const float* __restrict__ Wa, float* __restrict__ ws){
    __shared__ float smem[7488];   // xs[1024] Wds[4128] Was[2080] pbuf[256]
    int tid = threadIdx.x, lane = tid&31, grp = tid>>5, bid = blockIdx.x;
    if (bid >= 128){
        int4* zb = (int4*)(ws + O_NUMB);
        int t0 = (bid-128)*256 + tid, nthr = 896*256;
        int4 zz; zz.x=0; zz.y=0; zz.z=0; zz.w=0;
        for (int k=t0; k<ZERO_I4; k+=nthr) zb[k]=zz;
        return;
    }
    float* xs   = smem;            // [8][128]
    float* Wds  = smem + 1024;     // [32][129]
    float* Was  = smem + 5152;     // [32][65]
    float* pbuf = smem + 7232;     // [8][32]
    float* lamp = ws + O_LAMP;
    float* parr = ws + O_PARR;
    float* pn2  = ws + O_PN2;
    float* AB   = ws + O_AB;
    for (int idx=tid; idx<32*128; idx+=256) Wds[(idx>>7)*129+(idx&127)] = Wd[idx];
    for (int idx=tid; idx<32*63; idx+=256){ int k=idx/63, c=idx-63*k; Was[k*65+c]=Wa[idx]; }
    int node = bid*8 + grp;
#pragma unroll
    for (int r=0;r<4;++r) xs[grp*128+lane+32*r] = x[node*128+lane+32*r];
    __syncthreads();
    float ssp = 0.f;
#pragma unroll
    for (int r=0;r<4;++r){ int d=lane+32*r; float t=xs[grp*128+d]; if (d>=1) ssp += t*t; }
    float ss = rsum(ssp);
    float yn = sqrtf(fmaxf(ss, 1e-15f));
    float x0 = xs[grp*128];
    float scale = arcosh_f(x0)/yn;
    float acc = 0.f;
    for (int d=1; d<128; ++d) acc += Wds[lane*129+d]*xs[grp*128+d];
    float v = lane>=1 ? acc*scale : 0.f;
    float res = expmap0_proj_l(v, lane);
    float o   = mobius_add_u_l(res, bd[lane], lane);
    float o0 = __shfl(o, 0, 32);
    float p  = lane>=1 ? o/(o0+1.f) : 0.f;     // p_in
    float sq = rsum(p*p);
    float lam = 2.f/fmaxf(1.f-sq, 1e-15f);
    lamp[node*32+lane] = lane>=1 ? lam*p : lam-1.f;   // == in_emb row
    float wn = sqrtf(fmaxf(sq, 1e-15f));
    float attw = artanh_f(wn)/wn;
    parr[node*32+lane] = lane>=1 ? p : attw;
    if (lane==0) pn2[node] = sq;
    pbuf[grp*32+lane] = p;                     // group-private, intra-wave RAW
    float Ak = 0.f, Bk = 0.f;
    for (int d=1; d<32; ++d){
        float pd = pbuf[grp*32+d];
        Ak += Was[lane*65+d]*pd;
        Bk += Was[lane*65+31+d]*pd;
    }
    AB[node*64+lane]    = Ak;
    AB[node*64+32+lane] = Bk;
}

// ---- B: 256 blocks x 128 edges: es sums; claim cell; count row; partials ----
__global__ __launch_bounds__(256) void k_b(const int* __restrict__ edges,
        float* __restrict__ ws){
    __shared__ float parts[8*32];
    const float* pn2 = ws + O_PN2;
    const float* AB  = ws + O_AB;
    float* partial = ws + O_PART;
    int* slotmap = (int*)(ws + O_SLOT);
    int* cellcnt = (int*)(ws + O_CCNT);
    int* rowcnt  = (int*)(ws + O_ROWC);
    int tid = threadIdx.x, lane = tid&31, grp = tid>>5, bid = blockIdx.x;
    float colp = 0.f;
#pragma unroll
    for (int k=0;k<16;++k){
        int e = bid*128 + k*8 + grp;
        int i = edges[e], j = edges[EE+e];
        colp += edge_es(i, j, pn2, AB, lane);
        if (lane==0){
            int old = atomicAdd(&cellcnt[i*NN+j], 1);
            if (old==0){                       // first arriver claims cell
                slotmap[i*NN+j] = e;
                atomicAdd(&rowcnt[i], 1);      // unique cells per row
            }
        }
    }
    parts[grp*32+lane] = colp;
    __syncthreads();
    if (grp==0){
        float s8 = 0.f;
#pragma unroll
        for (int g=0; g<8; ++g) s8 += parts[g*32+lane];
        partial[bid*32+lane] = s8;             // coalesced, racefree
    }
}

// ---- D: colsum in LDS; softmax+att; dup last-arriver; node last-arriver epilogue ----
__global__ __launch_bounds__(256) void k_d(const int* __restrict__ edges,
        const float* __restrict__ Wo, const float* __restrict__ bo,
        float* __restrict__ out, float* __restrict__ ws){
    __shared__ float red[256];
    __shared__ float colsum_s[32];
    const float* partial = ws + O_PART;
    const float* pn2  = ws + O_PN2;
    const float* AB   = ws + O_AB;
    const float* parr = ws + O_PARR;
    const float* lamp = ws + O_LAMP;
    float* numb   = ws + O_NUMB;
    float* asum   = ws + O_ASUM;
    int* slotmap  = (int*)(ws + O_SLOT);
    int* cellcnt  = (int*)(ws + O_CCNT);
    int* rowcnt   = (int*)(ws + O_ROWC);
    int* ndep     = (int*)(ws + O_NDEP);
    int tid = threadIdx.x, lane = tid&31, grp = tid>>5, bid = blockIdx.x;
    // phase 1: reduce 256x32 partials -> colsum (per block, in LDS)
    {
        int col = tid&31, r0 = tid>>5;
        float s = 0.f;
#pragma unroll
        for (int m=0;m<32;++m) s += partial[(r0+8*m)*32+col];
        red[tid] = s;
        __syncthreads();
        if (grp==0){
            float s8 = 0.f;
#pragma unroll
            for (int g=0; g<8; ++g) s8 += red[g*32+lane];
            colsum_s[lane] = s8;
        }
        __syncthreads();
    }
    float csum = lane>=1 ? colsum_s[lane] : 1.f;
    // phase 2: 4 edges per group
#pragma unroll
    for (int k=0;k<4;++k){
        int e = bid*32 + k*8 + grp;
        int i = edges[e], j = edges[EE+e];
        float es = edge_es(i, j, pn2, AB, lane);
        float u = lane>=1 ? es/csum : 0.f;
        int cell = i*NN+j;
        int cnt = cellcnt[cell] & 0xFFFF;      // low 16 bits stable (k_b's count)
        bool contributed = false;
        if (cnt == 1){
            float th2 = rsum(u*u);
            float th = sqrtf(fmaxf(th2, 1e-15f));
            float f = tanhf(0.5f*th)/th;
            float pj = parr[j*32+lane];
            float attw = __shfl(pj, 0, 32);
            float dotu = rsum(lane>=1 ? u*pj : 0.f);
            float att = tanhf(f*dotu*attw);
            atomicAdd(&numb[i*32+lane], att*lamp[j*32+lane]);
            contributed = true;
        } else {
            float a = expmap0_proj_l(u, lane);
            int slot = slotmap[cell];
            atomicAdd(&asum[slot*32+lane], a);
            __threadfence();                   // wave-wide drain: deposits visible
            int old = 0;
            if (lane==0) old = atomicAdd(&cellcnt[cell], 0x10000);
            old = __shfl(old, 0, 32);
            if ((old>>16) == cnt-1){           // last arriver: sum complete
                __threadfence();
                float ac = __hip_atomic_load(&asum[slot*32+lane], __ATOMIC_RELAXED,
                                             __HIP_MEMORY_SCOPE_AGENT);
                float w  = lamp[j*32+lane];
                float att = att_of(ac, w, (float)cnt, lane);
                atomicAdd(&numb[i*32+lane], att*lamp[j*32+lane]);
                contributed = true;
            }
        }
        if (contributed){
            __threadfence();                   // my numb adds visible before bump
            int old = 0;
            if (lane==0) old = atomicAdd(&ndep[i], 1);
            old = __shfl(old, 0, 32);
            if (old+1 == rowcnt[i]){           // node complete: run epilogue here
                __threadfence();
                node_epilogue(i, lane, numb, Wo, bo, out);
            }
        }
    }
}

extern "C" void kernel_launch(void* const* d_in, const int* in_sizes, int n_in,
                              void* d_out, int out_size, void* d_ws, size_t ws_size,
                              hipStream_t stream) {
    const float* x  = (const float*)d_in[0];
    const int* edges = (const int*)d_in[1];
    const float* Wd = (const float*)d_in[2];
    const float* bd = (const float*)d_in[3];
    const float* Wa = (const float*)d_in[4];
    const float* Wo = (const float*)d_in[5];
    const float* bo = (const float*)d_in[6];
    float* out = (float*)d_out;
    float* ws  = (float*)d_ws;

    k_a<<<1024, 256, 0, stream>>>(x, Wd, bd, Wa, ws);
    k_b<<<256,  256, 0, stream>>>(edges, ws);
    k_d<<<1024, 256, 0, stream>>>(edges, Wo, bo, out, ws);
}

// Round 13
// 42.380 us; speedup vs baseline: 8.0301x; 8.0301x over previous
//
#include <hip/hip_runtime.h>
#include <math.h>

#define NN   1024
#define DD   32
#define EE   32768

// ---- workspace float offsets ----
#define O_LAMP 0             // NN*32  lamp: lane0=lam-1, 1..31=lam*p (== in_emb)
#define O_PARR 32768         // NN*32  parr: lane0=artanh(wn)/wn, 1..31=p_in
#define O_PN2  65536         // NN     |p_in|^2
#define O_AB   66560         // NN*64  per-node Wa half-dots [A(32) | B(32)]
#define O_NUMB 132096        // NN*32 (col0=den)        -- zero region start
#define O_PART 164864        // 256*32 colsum partials [blk&255][col]
#define O_CCNT 173056        // NN*NN ints: cell multiplicity -- zero region end
#define O_REPF 1221632       // EE ints: 1 if edge is its cell's representative
#define ZERO_I4 ((O_REPF - O_NUMB)/4)   // 272384 int4 = 4.36 MB

__device__ __forceinline__ float artanh_f(float x){
    x = fminf(fmaxf(x, -1.f + 1e-7f), 1.f - 1e-7f);
    return 0.5f * (log1pf(x) - log1pf(-x));
}
__device__ __forceinline__ float arcosh_f(float x){
    x = fmaxf(x, 1.f + 1e-7f);
    return logf(x + sqrtf(x*x - 1.f));
}
__device__ __forceinline__ float rsum(float v){
#pragma unroll
    for (int off=16; off>0; off>>=1) v += __shfl_xor(v, off, 32);
    return v;
}
__device__ __forceinline__ float logmap0_l(float xv, int lane){
    float ss = rsum(lane>=1 ? xv*xv : 0.f);
    float yn = sqrtf(fmaxf(ss, 1e-15f));
    float x0 = __shfl(xv, 0, 32);
    float s  = arcosh_f(x0) / yn;
    return lane>=1 ? s*xv : 0.f;
}
__device__ __forceinline__ float expmap0_proj_l(float uv, int lane){
    float ss = rsum(lane>=1 ? uv*uv : 0.f);
    float xn = sqrtf(fmaxf(ss, 1e-15f));
    float sh = sinhf(xn)/xn;
    float o  = sh*uv;
    float ys = rsum(lane>=1 ? o*o : 0.f);
    float o0 = sqrtf(fmaxf(1.f+ys, 1e-7f));
    return lane==0 ? o0 : o;
}
__device__ __forceinline__ float mobius_add_u_l(float xv, float uv, int lane){
    float u  = lane>=1 ? uv : 0.f;
    float x1 = lane>=1 ? xv : 0.f;
    float ss = rsum(x1*x1);
    float xn = sqrtf(fmaxf(ss, 1e-15f));
    float alpha = rsum(x1*u) / xn;
    float x0 = __shfl(xv, 0, 32);
    float coef = alpha * (1.f - x0) / xn;
    float w  = lane>=1 ? u - coef*xv : 0.f;
    float ux = rsum(x1*w);
    float w0 = ux / fmaxf(x0, 1e-7f);
    float wsq = rsum(w*w);
    float nu = sqrtf(fmaxf(wsq - w0*w0, 1e-15f));
    float th = fmaxf(nu, 1e-15f);
    float ch = coshf(th), shq = sinhf(th)/th;
    float o  = ch*xv + shq*w;
    float ys = rsum(lane>=1 ? o*o : 0.f);
    float o0 = sqrtf(fmaxf(1.f+ys, 1e-7f));
    return lane==0 ? o0 : o;
}
// att for a cell: ac = m*a (accumulated), w = lamp row (== in_emb row), mult m
__device__ __forceinline__ float att_of(float ac, float w, float m, int lane){
    float ad = __shfl(ac,0,32)+1.f;
    float wd = m*__shfl(w,0,32)+1.f;
    float pa_ = lane>=1 ? ac/ad : 0.f;
    float pw  = lane>=1 ? m*w/wd : 0.f;
    float dot = rsum(pa_*pw);
    float wns = rsum(pw*pw);
    float wn  = sqrtf(fmaxf(wns, 1e-15f));
    return tanhf(dot/wn * artanh_f(wn));
}
__device__ __forceinline__ float edge_es(int i, int j, const float* __restrict__ pn2,
        const float* __restrict__ AB, int lane){
    float sq = pn2[i] + pn2[j];
    float dnm = fmaxf(1.f-sq, 1e-15f);
    float c0  = (1.f+sq)/dnm;
    float ssy = 4.f*sq/(dnm*dnm);
    float ynn = sqrtf(fmaxf(ssy, 1e-15f));
    float scl = arcosh_f(c0)/ynn * 2.f/dnm;     // sc2 * t2
    float v = scl*(AB[i*64+lane] + AB[j*64+32+lane]);
    v = v>=0.f ? v : 0.2f*v;                    // leaky (logmap/expmap cancel)
    return lane>=1 ? expf(v) : 0.f;             // bounded logits: no max pass
}

// ---- A: fill (blocks 128..1023) + per-node precompute (blocks 0..127) ----
__global__ __launch_bounds__(256) void k_a(const float* __restrict__ x,
        const float* __restrict__ Wd, const float* __restrict__ bd,
        const float* __restrict__ Wa, float* __restrict__ ws){
    __shared__ float smem[7488];   // xs[1024] Wds[4128] Was[2080] pbuf[256]
    int tid = threadIdx.x, lane = tid&31, grp = tid>>5, bid = blockIdx.x;
    if (bid >= 128){
        int4* zb = (int4*)(ws + O_NUMB);
        int t0 = (bid-128)*256 + tid, nthr = 896*256;
        int4 zz; zz.x=0; zz.y=0; zz.z=0; zz.w=0;
        for (int k=t0; k<ZERO_I4; k+=nthr) zb[k]=zz;
        return;
    }
    float* xs   = smem;            // [8][128]
    float* Wds  = smem + 1024;     // [32][129]
    float* Was  = smem + 5152;     // [32][65]
    float* pbuf = smem + 7232;     // [8][32]
    float* lamp = ws + O_LAMP;
    float* parr = ws + O_PARR;
    float* pn2  = ws + O_PN2;
    float* AB   = ws + O_AB;
    for (int idx=tid; idx<32*128; idx+=256) Wds[(idx>>7)*129+(idx&127)] = Wd[idx];
    for (int idx=tid; idx<32*63; idx+=256){ int k=idx/63, c=idx-63*k; Was[k*65+c]=Wa[idx]; }
    int node = bid*8 + grp;
#pragma unroll
    for (int r=0;r<4;++r) xs[grp*128+lane+32*r] = x[node*128+lane+32*r];
    __syncthreads();
    float ssp = 0.f;
#pragma unroll
    for (int r=0;r<4;++r){ int d=lane+32*r; float t=xs[grp*128+d]; if (d>=1) ssp += t*t; }
    float ss = rsum(ssp);
    float yn = sqrtf(fmaxf(ss, 1e-15f));
    float x0 = xs[grp*128];
    float scale = arcosh_f(x0)/yn;
    float acc = 0.f;
    for (int d=1; d<128; ++d) acc += Wds[lane*129+d]*xs[grp*128+d];
    float v = lane>=1 ? acc*scale : 0.f;
    float res = expmap0_proj_l(v, lane);
    float o   = mobius_add_u_l(res, bd[lane], lane);
    float o0 = __shfl(o, 0, 32);
    float p  = lane>=1 ? o/(o0+1.f) : 0.f;     // p_in
    float sq = rsum(p*p);
    float lam = 2.f/fmaxf(1.f-sq, 1e-15f);
    lamp[node*32+lane] = lane>=1 ? lam*p : lam-1.f;   // == in_emb row
    float wn = sqrtf(fmaxf(sq, 1e-15f));
    float attw = artanh_f(wn)/wn;
    parr[node*32+lane] = lane>=1 ? p : attw;
    if (lane==0) pn2[node] = sq;
    pbuf[grp*32+lane] = p;                     // group-private, intra-wave RAW
    float Ak = 0.f, Bk = 0.f;
    for (int d=1; d<32; ++d){
        float pd = pbuf[grp*32+d];
        Ak += Was[lane*65+d]*pd;
        Bk += Was[lane*65+31+d]*pd;
    }
    AB[node*64+lane]    = Ak;
    AB[node*64+32+lane] = Bk;
}

// ---- B: per-edge es sums; cell multiplicity count; rep claim; colsum partials ----
__global__ __launch_bounds__(256) void k_b(const int* __restrict__ edges,
        float* __restrict__ ws){
    __shared__ float parts[8*32];
    const float* pn2 = ws + O_PN2;
    const float* AB  = ws + O_AB;
    float* partial = ws + O_PART;
    int* cellcnt = (int*)(ws + O_CCNT);
    int* repflag = (int*)(ws + O_REPF);
    int tid = threadIdx.x, lane = tid&31, grp = tid>>5, bid = blockIdx.x;
    float colp = 0.f;
#pragma unroll
    for (int k=0;k<4;++k){
        int e = bid*32 + k*8 + grp;
        int i = edges[e], j = edges[EE+e];
        colp += edge_es(i, j, pn2, AB, lane);
        if (lane==0){
            int old = atomicAdd(&cellcnt[i*NN+j], 1);
            repflag[e] = (old==0) ? 1 : 0;     // first arriver represents the cell
        }
    }
    parts[grp*32+lane] = colp;
    __syncthreads();
    if (grp==0){
        float s8 = 0.f;
#pragma unroll
        for (int g=0; g<8; ++g) s8 += parts[g*32+lane];
        atomicAdd(&partial[(bid&255)*32+lane], s8);   // chain depth <= 4
    }
}

// ---- D: LDS colsum; representative edges compute att (m-scaled); numb adds ----
__global__ __launch_bounds__(256) void k_d(const int* __restrict__ edges,
        float* __restrict__ ws){
    __shared__ float red[256];
    __shared__ float colsum_s[32];
    const float* partial = ws + O_PART;
    const float* pn2  = ws + O_PN2;
    const float* AB   = ws + O_AB;
    const float* parr = ws + O_PARR;
    const float* lamp = ws + O_LAMP;
    float* numb   = ws + O_NUMB;
    int* cellcnt  = (int*)(ws + O_CCNT);
    int* repflag  = (int*)(ws + O_REPF);
    int tid = threadIdx.x, lane = tid&31, grp = tid>>5, bid = blockIdx.x;
    // phase 1: reduce 256x32 partials -> colsum (per block, in LDS; ~32KB L2/block)
    {
        int col = tid&31, r0 = tid>>5;
        float s = 0.f;
#pragma unroll
        for (int m=0;m<32;++m) s += partial[(r0+8*m)*32+col];
        red[tid] = s;
        __syncthreads();
        if (grp==0){
            float s8 = 0.f;
#pragma unroll
            for (int g=0; g<8; ++g) s8 += red[g*32+lane];
            colsum_s[lane] = s8;
        }
        __syncthreads();
    }
    float csum = lane>=1 ? colsum_s[lane] : 1.f;
    // phase 2: only representative edges do work
#pragma unroll
    for (int k=0;k<4;++k){
        int e = bid*32 + k*8 + grp;
        if (!repflag[e]) continue;             // group-uniform predicate
        int i = edges[e], j = edges[EE+e];
        float es = edge_es(i, j, pn2, AB, lane);
        float u = lane>=1 ? es/csum : 0.f;
        int m = cellcnt[i*NN+j];               // final multiplicity
        float att;
        if (m == 1){
            float th2 = rsum(u*u);
            float th = sqrtf(fmaxf(th2, 1e-15f));
            float f = tanhf(0.5f*th)/th;
            float pj = parr[j*32+lane];
            float attw = __shfl(pj, 0, 32);
            float dotu = rsum(lane>=1 ? u*pj : 0.f);
            att = tanhf(f*dotu*attw);
        } else {
            // duplicates have identical a -> cell sum = m*a, w_masked = m*in_emb[j]
            float a = expmap0_proj_l(u, lane);
            float w = lamp[j*32+lane];
            att = att_of(m*a, w, (float)m, lane);
        }
        atomicAdd(&numb[i*32+lane], att*lamp[j*32+lane]);
    }
}

// ---- F: per-node epilogue ----
__global__ __launch_bounds__(256) void k_f(const float* __restrict__ Wo,
        const float* __restrict__ bo, float* __restrict__ out,
        float* __restrict__ ws){
    __shared__ float Wos[32*33];
    const float* numb = ws + O_NUMB;
    int tid = threadIdx.x, lane = tid&31, grp = tid>>5;
    int i = blockIdx.x*8 + grp;
    for (int idx=tid; idx<1024; idx+=256) Wos[(idx>>5)*33+(idx&31)] = Wo[idx];
    __syncthreads();
    float nb = numb[i*32+lane];
    float dn = __shfl(nb, 0, 32);
    if (fabsf(dn) < 1e-10f) dn = 1e-10f;
    float g = lane>=1 ? nb/dn : 0.f;
    float gss = rsum(g*g);
    float gn = sqrtf(fmaxf(gss, 1e-15f));
    float scl = tanhf(0.5f*artanh_f(gn))/gn;
    g *= scl;                                   // p_out
    float sq = rsum(g*g);
    float dnm = fmaxf(1.f-sq, 1e-15f);
    float h = lane==0 ? (1.f+sq)/dnm : 2.f*g/dnm;
    float r = logmap0_l(h, lane);
    float acc = 0.f;
#pragma unroll
    for (int d=1; d<32; ++d){ float rb = __shfl(r, d, 32); acc += Wos[lane*33+d]*rb; }
    float v = lane>=1 ? acc : 0.f;
    float res = expmap0_proj_l(v, lane);
    float o   = mobius_add_u_l(res, bo[lane], lane);
    out[i*32+lane] = o;
}

extern "C" void kernel_launch(void* const* d_in, const int* in_sizes, int n_in,
                              void* d_out, int out_size, void* d_ws, size_t ws_size,
                              hipStream_t stream) {
    const float* x  = (const float*)d_in[0];
    const int* edges = (const int*)d_in[1];
    const float* Wd = (const float*)d_in[2];
    const float* bd = (const float*)d_in[3];
    const float* Wa = (const float*)d_in[4];
    const float* Wo = (const float*)d_in[5];
    const float* bo = (const float*)d_in[6];
    float* out = (float*)d_out;
    float* ws  = (float*)d_ws;

    k_a<<<1024, 256, 0, stream>>>(x, Wd, bd, Wa, ws);
    k_b<<<1024, 256, 0, stream>>>(edges, ws);
    k_d<<<1024, 256, 0, stream>>>(edges, ws);
    k_f<<<NN/8, 256, 0, stream>>>(Wo, bo, out, ws);
}